// Round 1
// baseline (321.303 us; speedup 1.0000x reference)
//
#include <hip/hip_runtime.h>

typedef _Float16 f16;
typedef _Float16 f16x8 __attribute__((ext_vector_type(8)));
typedef _Float16 f16x4 __attribute__((ext_vector_type(4)));
typedef float    f32x4 __attribute__((ext_vector_type(4)));

#define MFMA16(a, b, c) __builtin_amdgcn_mfma_f32_16x16x32_f16((a), (b), (c), 0, 0, 0)

constexpr int T = 64;    // sequence length
constexpr int C = 384;   // n_embd
constexpr int H = 64;    // head size
constexpr float SCALE = 3.26598632371090f;  // 64 * 384^-0.5

// ---------------------------------------------------------------------------
// Pack Wk,Wq,Wv (fp32 [64][384]) into f16 MFMA-fragment order in d_ws.
// Layout: Wp[((wi*12 + kt)*4 + ht)*512 + lane*8 + j]
//   = W_wi[16*ht + (lane&15)][32*kt + 8*(lane>>4) + j]
// This is simultaneously the A-frag (m=lane&15, k=quad*8+j) and B-frag
// (n=lane&15, k=quad*8+j) layout for 16x16x32 MFMA.
// ---------------------------------------------------------------------------
__global__ void pack_w(const float* __restrict__ Wk, const float* __restrict__ Wq,
                       const float* __restrict__ Wv, f16* __restrict__ Wp) {
  int tid = blockIdx.x * blockDim.x + threadIdx.x;
  if (tid >= 3 * 12 * 4 * 64) return;
  int lane = tid & 63;
  int tile = tid >> 6;          // (wi*12 + kt)*4 + ht
  int ht = tile & 3;
  int kt = (tile >> 2) % 12;
  int wi = tile / 48;
  const float* W = (wi == 0) ? Wk : ((wi == 1) ? Wq : Wv);
  int h = 16 * ht + (lane & 15);
  int c = 32 * kt + 8 * (lane >> 4);
  const float* src = W + h * C + c;
  f16x8 v;
#pragma unroll
  for (int j = 0; j < 8; ++j) v[j] = (f16)src[j];
  *(f16x8*)(Wp + (size_t)tile * 512 + lane * 8) = v;
}

// ---------------------------------------------------------------------------
// Fused head kernel: one block per batch, 4 waves, wave w owns t-strip
// [16w, 16w+16). f16 MFMA for projections/QK^T/PV, fp32 softmax.
// ---------------------------------------------------------------------------
__global__ __launch_bounds__(256, 4) void head_fused(
    const float* __restrict__ x, const f16* __restrict__ Wp,
    float* __restrict__ out) {
  // pitch 72 f16 = 36 dwords; 36 % 32 = 4 -> <=2-way LDS bank aliasing (free)
  __shared__ f16 q_lds[64][72];   // q[t][h]
  __shared__ f16 k_lds[64][72];   // k[t][h]
  __shared__ f16 vT_lds[64][72];  // v^T[h][t]
  __shared__ f16 p_lds[64][72];   // P[t][s]

  const int b = blockIdx.x;
  const int tid = threadIdx.x;
  const int w = tid >> 6;       // wave 0..3
  const int lane = tid & 63;
  const int l15 = lane & 15;
  const int g = lane >> 4;      // quad 0..3
  const int t_ = 16 * w + l15;  // this lane's t (column role in D-layout)

  const f32x4 vzero = {0.0f, 0.0f, 0.0f, 0.0f};
  f32x4 accq[4], acck[4], accv[4];
#pragma unroll
  for (int i = 0; i < 4; ++i) { accq[i] = vzero; acck[i] = vzero; accv[i] = vzero; }

  // ---- Phase 1: projections. qT = Wq.x^T, kT = Wk.x^T (W as A, x as B);
  //      v = x.Wv^T (x as A, Wv as B). Same x fragment serves all three.
  const float* xrow = x + ((size_t)b * T + t_) * C;
  const f16* wp_lane = Wp + lane * 8;

#pragma unroll 1
  for (int kt = 0; kt < 12; ++kt) {
    const f32x4 a0 = *(const f32x4*)(xrow + kt * 32 + g * 8);
    const f32x4 a1 = *(const f32x4*)(xrow + kt * 32 + g * 8 + 4);
    f16x8 xf;
#pragma unroll
    for (int j = 0; j < 4; ++j) { xf[j] = (f16)a0[j]; xf[4 + j] = (f16)a1[j]; }

    const f16* wk_base = wp_lane + (size_t)(0 * 12 + kt) * 4 * 512;
    const f16* wq_base = wp_lane + (size_t)(1 * 12 + kt) * 4 * 512;
    const f16* wv_base = wp_lane + (size_t)(2 * 12 + kt) * 4 * 512;
#pragma unroll
    for (int ht = 0; ht < 4; ++ht) {
      f16x8 wqf = *(const f16x8*)(wq_base + ht * 512);
      accq[ht] = MFMA16(wqf, xf, accq[ht]);   // D[h][t] tile
    }
#pragma unroll
    for (int ht = 0; ht < 4; ++ht) {
      f16x8 wkf = *(const f16x8*)(wk_base + ht * 512);
      acck[ht] = MFMA16(wkf, xf, acck[ht]);
    }
#pragma unroll
    for (int ht = 0; ht < 4; ++ht) {
      f16x8 wvf = *(const f16x8*)(wv_base + ht * 512);
      accv[ht] = MFMA16(xf, wvf, accv[ht]);   // D[t][h] tile
    }
  }

  // D-layout: col = lane&15, row = 4*quad + r. All writes 4-contiguous (b64).
#pragma unroll
  for (int ht = 0; ht < 4; ++ht) {
    f16x4 pq, pk, pv;
#pragma unroll
    for (int r = 0; r < 4; ++r) {
      pq[r] = (f16)accq[ht][r];
      pk[r] = (f16)acck[ht][r];
      pv[r] = (f16)accv[ht][r];
    }
    *(f16x4*)&q_lds[t_][16 * ht + 4 * g] = pq;        // q[t][h], h = 16ht+4g+r
    *(f16x4*)&k_lds[t_][16 * ht + 4 * g] = pk;
    *(f16x4*)&vT_lds[16 * ht + l15][16 * w + 4 * g] = pv;  // vT[h][t], t = 16w+4g+r
  }
  __syncthreads();

  // ---- Phase 2: S^T = k.q^T  (=> lane holds column t of S, 16 s-entries)
  f32x4 accs[4];
#pragma unroll
  for (int i = 0; i < 4; ++i) accs[i] = vzero;
#pragma unroll
  for (int kt = 0; kt < 2; ++kt) {
    f16x8 qf = *(const f16x8*)&q_lds[t_][32 * kt + 8 * g];
#pragma unroll
    for (int mt = 0; mt < 4; ++mt) {
      f16x8 kf = *(const f16x8*)&k_lds[16 * mt + l15][32 * kt + 8 * g];
      accs[mt] = MFMA16(kf, qf, accs[mt]);  // D[s][t]: s = 16mt+4g+r, t = t_
    }
  }

  // ---- Phase 3: causal mask + softmax over s (per column t, fp32)
  float e[16];
  float mx = -__builtin_inff();
#pragma unroll
  for (int mt = 0; mt < 4; ++mt) {
#pragma unroll
    for (int r = 0; r < 4; ++r) {
      int s = 16 * mt + 4 * g + r;
      float lv = accs[mt][r] * SCALE;
      lv = (s <= t_) ? lv : -__builtin_inff();
      e[mt * 4 + r] = lv;
      mx = fmaxf(mx, lv);
    }
  }
  mx = fmaxf(mx, __shfl_xor(mx, 16));
  mx = fmaxf(mx, __shfl_xor(mx, 32));
  float sm = 0.0f;
#pragma unroll
  for (int i = 0; i < 16; ++i) { e[i] = __expf(e[i] - mx); sm += e[i]; }
  sm += __shfl_xor(sm, 16);
  sm += __shfl_xor(sm, 32);
  const float inv = 1.0f / sm;
#pragma unroll
  for (int mt = 0; mt < 4; ++mt) {
    f16x4 pp;
#pragma unroll
    for (int r = 0; r < 4; ++r) pp[r] = (f16)(e[mt * 4 + r] * inv);
    *(f16x4*)&p_lds[t_][16 * mt + 4 * g] = pp;  // P[t][s], s = 16mt+4g+r
  }
  __syncthreads();

  // ---- Phase 4: out^T = v^T . P^T  (A = vT, B-frag from P[t][s])
  f32x4 acco[4];
#pragma unroll
  for (int i = 0; i < 4; ++i) acco[i] = vzero;
#pragma unroll
  for (int kt = 0; kt < 2; ++kt) {
    f16x8 pf = *(const f16x8*)&p_lds[t_][32 * kt + 8 * g];
#pragma unroll
    for (int mt = 0; mt < 4; ++mt) {
      f16x8 vf = *(const f16x8*)&vT_lds[16 * mt + l15][32 * kt + 8 * g];
      acco[mt] = MFMA16(vf, pf, acco[mt]);  // D[h][t]: h = 16mt+4g+r, t = t_
    }
  }

  // ---- store: out[b][t][h] fp32, 4 consecutive h per reg quad -> float4
  float* orow = out + ((size_t)b * T + t_) * H;
#pragma unroll
  for (int mt = 0; mt < 4; ++mt) {
    *(f32x4*)(orow + 16 * mt + 4 * g) = acco[mt];
  }
}

extern "C" void kernel_launch(void* const* d_in, const int* in_sizes, int n_in,
                              void* d_out, int out_size, void* d_ws, size_t ws_size,
                              hipStream_t stream) {
  const float* x  = (const float*)d_in[0];
  const float* Wk = (const float*)d_in[1];
  const float* Wq = (const float*)d_in[2];
  const float* Wv = (const float*)d_in[3];
  float* out = (float*)d_out;
  f16* Wp = (f16*)d_ws;  // 3*12*4*64*8 f16 = 147456 B

  // Re-pack every launch: d_ws is re-poisoned before each timed call.
  pack_w<<<36, 256, 0, stream>>>(Wk, Wq, Wv, Wp);
  head_fused<<<2048, 256, 0, stream>>>(x, Wp, out);
}